// Round 1
// baseline (86.919 us; speedup 1.0000x reference)
//
#include <hip/hip_runtime.h>

#define N_TOTAL   4096
#define N_NODES   1024
#define N_MARBLES 3072
#define N_EATERS  64
#define EPS       1e-6f
#define TILE      256
#define JCHUNKS   (N_TOTAL / TILE)   // 16

// Kernel 1: partial accelerations.
// grid = (N_TOTAL/TILE, JCHUNKS), block = TILE threads.
// partial[(jc*N_TOTAL + i)*2 + {0,1}] = sum over j in chunk jc of
//   m_j * (d2+EPS)^{-1.5} * (p_j - p_i)   (zeroed where d2 == 0)
__global__ __launch_bounds__(TILE) void force_partial(
    const float* __restrict__ pos, const float* __restrict__ mass,
    float* __restrict__ partial)
{
    __shared__ float sx[TILE], sy[TILE], sm[TILE];
    const int i  = blockIdx.x * TILE + threadIdx.x;
    const int jc = blockIdx.y;
    const int jl = jc * TILE + threadIdx.x;

    sx[threadIdx.x] = pos[jl * 2 + 0];
    sy[threadIdx.x] = pos[jl * 2 + 1];
    sm[threadIdx.x] = mass[jl];
    __syncthreads();

    const float pxi = pos[i * 2 + 0];
    const float pyi = pos[i * 2 + 1];
    float ax = 0.f, ay = 0.f;

#pragma unroll 8
    for (int j = 0; j < TILE; ++j) {
        float dx = sx[j] - pxi;
        float dy = sy[j] - pyi;
        float d2 = dx * dx + dy * dy;
        float t  = d2 + EPS;
        float r  = rsqrtf(t);
        r = r * (1.5f - 0.5f * t * r * r);     // Newton refine: ~full fp32 accuracy
        float w = r * r * r * sm[j];           // m_j * t^{-1.5}
        w = (d2 > 0.f) ? w : 0.f;              // matches reference dist2>0 mask
        ax = fmaf(w, dx, ax);
        ay = fmaf(w, dy, ay);
    }

    partial[(jc * N_TOTAL + i) * 2 + 0] = ax;
    partial[(jc * N_TOTAL + i) * 2 + 1] = ay;
}

// Kernel 2: reduce partials, Euler step, write state_new = [pos_new; vel_new].
__global__ __launch_bounds__(TILE) void integrate(
    const float* __restrict__ pos, const float* __restrict__ vel,
    const float* __restrict__ partial, const float* __restrict__ dtp,
    float* __restrict__ out)
{
    const int i = blockIdx.x * blockDim.x + threadIdx.x;
    const float dt = dtp[0];

    float ax = 0.f, ay = 0.f;
#pragma unroll
    for (int jc = 0; jc < JCHUNKS; ++jc) {
        ax += partial[(jc * N_TOTAL + i) * 2 + 0];
        ay += partial[(jc * N_TOTAL + i) * 2 + 1];
    }

    const float vx = vel[i * 2 + 0] + ax * dt;
    const float vy = vel[i * 2 + 1] + ay * dt;
    const float px = pos[i * 2 + 0] + vx * dt;
    const float py = pos[i * 2 + 1] + vy * dt;

    out[i * 2 + 0] = px;                       // pos_new
    out[i * 2 + 1] = py;
    out[2 * N_TOTAL + i * 2 + 0] = vx;         // vel_new
    out[2 * N_TOTAL + i * 2 + 1] = vy;
}

// Kernel 3: marble-vs-eater proximity. Reads pos_new from out (same stream ->
// ordered after integrate). Writes 1.0/0.0 at out + 4*N_TOTAL.
__global__ __launch_bounds__(TILE) void eaten_kernel(
    const float* __restrict__ out_state, const int* __restrict__ eater_idx,
    const float* __restrict__ eater_radius, float* __restrict__ out_eaten)
{
    __shared__ float ex[N_EATERS], ey[N_EATERS], er2[N_EATERS];
    if (threadIdx.x < N_EATERS) {
        const int idx = eater_idx[threadIdx.x];
        ex[threadIdx.x] = out_state[idx * 2 + 0];
        ey[threadIdx.x] = out_state[idx * 2 + 1];
        const float r = eater_radius[threadIdx.x];
        er2[threadIdx.x] = r * r;
    }
    __syncthreads();

    const int m = blockIdx.x * blockDim.x + threadIdx.x;
    const float mx = out_state[(N_NODES + m) * 2 + 0];
    const float my = out_state[(N_NODES + m) * 2 + 1];

    bool any = false;
#pragma unroll
    for (int e = 0; e < N_EATERS; ++e) {
        const float dx = mx - ex[e];
        const float dy = my - ey[e];
        any = any || (dx * dx + dy * dy <= er2[e]);
    }
    out_eaten[m] = any ? 1.0f : 0.0f;
}

extern "C" void kernel_launch(void* const* d_in, const int* in_sizes, int n_in,
                              void* d_out, int out_size, void* d_ws, size_t ws_size,
                              hipStream_t stream) {
    const float* pos  = (const float*)d_in[0];   // (4096, 2)
    const float* vel  = (const float*)d_in[1];   // (4096, 2)
    const float* mass = (const float*)d_in[2];   // (4096,)
    const int*   eidx = (const int*)d_in[3];     // (64,)
    const float* erad = (const float*)d_in[4];   // (64,)
    const float* dt   = (const float*)d_in[5];   // (1,)

    float* out     = (float*)d_out;              // 16384 state + 3072 eaten
    float* partial = (float*)d_ws;               // 16*4096*2 f32 = 512 KB

    dim3 g1(N_TOTAL / TILE, JCHUNKS);            // (16, 16)
    force_partial<<<g1, TILE, 0, stream>>>(pos, mass, partial);
    integrate<<<N_TOTAL / TILE, TILE, 0, stream>>>(pos, vel, partial, dt, out);
    eaten_kernel<<<N_MARBLES / TILE, TILE, 0, stream>>>(out, eidx, erad,
                                                        out + 4 * N_TOTAL);
}

// Round 2
// 79.629 us; speedup vs baseline: 1.0916x; 1.0916x over previous
//
#include <hip/hip_runtime.h>

#define N_TOTAL   4096
#define N_NODES   1024
#define N_MARBLES 3072
#define N_EATERS  64
#define EPS       1e-6f
#define BLOCK     256
#define JCHUNK    64                  // j's per block
#define JCHUNKS   (N_TOTAL / JCHUNK) // 64

// Kernel 1: partial accelerations.
// grid = (N_TOTAL/BLOCK, JCHUNKS) = (16, 64), block = 256 threads.
// Each block: 256 i's x 64 j's. j-index is wave-uniform -> scalar loads,
// no LDS, no __syncthreads. Contribution of d2==0 pairs is exactly 0
// (dx=dy=0, finite w), so no mask needed.
__global__ __launch_bounds__(BLOCK) void force_partial(
    const float* __restrict__ pos, const float* __restrict__ mass,
    float* __restrict__ partial)
{
    const int i  = blockIdx.x * BLOCK + threadIdx.x;
    const int j0 = blockIdx.y * JCHUNK;

    const float pxi = pos[i * 2 + 0];
    const float pyi = pos[i * 2 + 1];
    float ax = 0.f, ay = 0.f;

#pragma unroll 16
    for (int j = j0; j < j0 + JCHUNK; ++j) {
        const float dx = pos[j * 2 + 0] - pxi;   // uniform index -> s_load
        const float dy = pos[j * 2 + 1] - pyi;
        const float t  = fmaf(dx, dx, fmaf(dy, dy, EPS));  // d2 + EPS
        const float r  = rsqrtf(t);
        const float w  = r * r * r * mass[j];    // m_j * t^{-1.5}
        ax = fmaf(w, dx, ax);
        ay = fmaf(w, dy, ay);
    }

    partial[(blockIdx.y * N_TOTAL + i) * 2 + 0] = ax;
    partial[(blockIdx.y * N_TOTAL + i) * 2 + 1] = ay;
}

// Kernel 2: reduce partials, Euler step, write state_new = [pos_new; vel_new].
__global__ __launch_bounds__(BLOCK) void integrate(
    const float* __restrict__ pos, const float* __restrict__ vel,
    const float* __restrict__ partial, const float* __restrict__ dtp,
    float* __restrict__ out)
{
    const int i = blockIdx.x * blockDim.x + threadIdx.x;
    const float dt = dtp[0];

    const float2* __restrict__ p2 = (const float2*)partial;
    float ax = 0.f, ay = 0.f;
#pragma unroll 16
    for (int jc = 0; jc < JCHUNKS; ++jc) {
        const float2 p = p2[jc * N_TOTAL + i];
        ax += p.x;
        ay += p.y;
    }

    const float vx = vel[i * 2 + 0] + ax * dt;
    const float vy = vel[i * 2 + 1] + ay * dt;
    const float px = pos[i * 2 + 0] + vx * dt;
    const float py = pos[i * 2 + 1] + vy * dt;

    out[i * 2 + 0] = px;                       // pos_new
    out[i * 2 + 1] = py;
    out[2 * N_TOTAL + i * 2 + 0] = vx;         // vel_new
    out[2 * N_TOTAL + i * 2 + 1] = vy;
}

// Kernel 3: marble-vs-eater proximity. Reads pos_new from out (same stream ->
// ordered after integrate). Writes 1.0/0.0 at out + 4*N_TOTAL.
__global__ __launch_bounds__(BLOCK) void eaten_kernel(
    const float* __restrict__ out_state, const int* __restrict__ eater_idx,
    const float* __restrict__ eater_radius, float* __restrict__ out_eaten)
{
    __shared__ float ex[N_EATERS], ey[N_EATERS], er2[N_EATERS];
    if (threadIdx.x < N_EATERS) {
        const int idx = eater_idx[threadIdx.x];
        ex[threadIdx.x] = out_state[idx * 2 + 0];
        ey[threadIdx.x] = out_state[idx * 2 + 1];
        const float r = eater_radius[threadIdx.x];
        er2[threadIdx.x] = r * r;
    }
    __syncthreads();

    const int m = blockIdx.x * blockDim.x + threadIdx.x;
    const float mx = out_state[(N_NODES + m) * 2 + 0];
    const float my = out_state[(N_NODES + m) * 2 + 1];

    bool any = false;
#pragma unroll
    for (int e = 0; e < N_EATERS; ++e) {
        const float dx = mx - ex[e];
        const float dy = my - ey[e];
        any = any || (dx * dx + dy * dy <= er2[e]);
    }
    out_eaten[m] = any ? 1.0f : 0.0f;
}

extern "C" void kernel_launch(void* const* d_in, const int* in_sizes, int n_in,
                              void* d_out, int out_size, void* d_ws, size_t ws_size,
                              hipStream_t stream) {
    const float* pos  = (const float*)d_in[0];   // (4096, 2)
    const float* vel  = (const float*)d_in[1];   // (4096, 2)
    const float* mass = (const float*)d_in[2];   // (4096,)
    const int*   eidx = (const int*)d_in[3];     // (64,)
    const float* erad = (const float*)d_in[4];   // (64,)
    const float* dt   = (const float*)d_in[5];   // (1,)

    float* out     = (float*)d_out;              // 16384 state + 3072 eaten
    float* partial = (float*)d_ws;               // 64*4096*2 f32 = 2 MB

    dim3 g1(N_TOTAL / BLOCK, JCHUNKS);           // (16, 64)
    force_partial<<<g1, BLOCK, 0, stream>>>(pos, mass, partial);
    integrate<<<N_TOTAL / BLOCK, BLOCK, 0, stream>>>(pos, vel, partial, dt, out);
    eaten_kernel<<<N_MARBLES / BLOCK, BLOCK, 0, stream>>>(out, eidx, erad,
                                                          out + 4 * N_TOTAL);
}